// Round 6
// baseline (632.981 us; speedup 1.0000x reference)
//
#include <hip/hip_runtime.h>
#include <hip/hip_fp16.h>
#include <math.h>

#define NN 100000
#define NE 3200000
#define FIN 128
#define HD 64
#define TOUT 16
#define NB_SCAN ((NN + 255) / 256)   // 391
#define BSH 8                        // 256 nodes per bucket
#define NBUK ((NN + 255) / 256)      // 391 buckets
#define EPB 8192                     // edges per P1 block

// ---------------- degree ----------------
__global__ __launch_bounds__(256) void k_deg(const int* __restrict__ dst, unsigned* __restrict__ deg) {
  int e = blockIdx.x * 256 + threadIdx.x;
  if (e < NE) atomicAdd(&deg[dst[e]], 1u);
}

__global__ __launch_bounds__(256) void k_dinv(const unsigned* __restrict__ deg, float* __restrict__ dinv) {
  int i = blockIdx.x * 256 + threadIdx.x;
  if (i < NN) dinv[i] = 1.0f / sqrtf((float)deg[i] + 1.0f);  // +1 self-loop
}

// ---------------- exclusive scan (3 phases) ----------------
__global__ __launch_bounds__(256) void k_scan_local(const unsigned* __restrict__ deg,
                                                    int* __restrict__ rowptr,
                                                    unsigned* __restrict__ blockSum) {
  __shared__ unsigned s[256];
  int t = threadIdx.x, i = blockIdx.x * 256 + t;
  unsigned v = (i < NN) ? deg[i] : 0u;
  s[t] = v;
  __syncthreads();
  for (int off = 1; off < 256; off <<= 1) {
    unsigned y = (t >= off) ? s[t - off] : 0u;
    __syncthreads();
    s[t] += y;
    __syncthreads();
  }
  if (i < NN) rowptr[i] = (int)(s[t] - v);
  if (t == 255) blockSum[blockIdx.x] = s[255];
}

__global__ __launch_bounds__(512) void k_scan_block(unsigned* __restrict__ blockSum) {
  __shared__ unsigned s[512];
  int t = threadIdx.x;
  unsigned v = (t < NB_SCAN) ? blockSum[t] : 0u;
  s[t] = v;
  __syncthreads();
  for (int off = 1; off < 512; off <<= 1) {
    unsigned y = (t >= off) ? s[t - off] : 0u;
    __syncthreads();
    s[t] += y;
    __syncthreads();
  }
  if (t < NB_SCAN) blockSum[t] = s[t] - v;
}

__global__ __launch_bounds__(256) void k_scan_add(int* __restrict__ rowptr, const unsigned* __restrict__ blockSum,
                                                  int* __restrict__ bcur) {
  int i = blockIdx.x * 256 + threadIdx.x;
  if (i < NN) {
    int r = rowptr[i] + (int)blockSum[i >> 8];
    rowptr[i] = r;
    if ((i & 255) == 0) bcur[i >> BSH] = r;
  }
  if (i == 0) rowptr[NN] = NE;
}

// ---------------- P1: block-local histogram + contiguous run reservation ----------------
__global__ __launch_bounds__(256) void k_p1(const int* __restrict__ src, const int* __restrict__ dst,
                                            int* __restrict__ bcur, unsigned* __restrict__ packed) {
  __shared__ int hist[NBUK];
  __shared__ int base[NBUK];
  int t = threadIdx.x;
  int e0 = blockIdx.x * EPB;
  int e1 = e0 + EPB; if (e1 > NE) e1 = NE;

  for (int i = t; i < NBUK; i += 256) hist[i] = 0;
  __syncthreads();
  for (int e = e0 + t; e < e1; e += 256) atomicAdd(&hist[dst[e] >> BSH], 1);
  __syncthreads();
  for (int i = t; i < NBUK; i += 256) {
    int c = hist[i];
    base[i] = c ? atomicAdd(&bcur[i], c) : 0;
    hist[i] = 0;
  }
  __syncthreads();
  for (int e = e0 + t; e < e1; e += 256) {
    int d = dst[e];
    int b = d >> BSH;
    int p = base[b] + atomicAdd(&hist[b], 1);
    packed[p] = ((unsigned)(d & 255) << 17) | (unsigned)src[e];
  }
}

// ---------------- P2: node-exact CSR within each bucket ----------------
__global__ __launch_bounds__(256) void k_p2(const unsigned* __restrict__ packed, const int* __restrict__ rowptr,
                                            int* __restrict__ csr_src) {
  __shared__ int cur[256];
  int b = blockIdx.x;
  int node0 = b << BSH;
  int node1 = node0 + 256; if (node1 > NN) node1 = NN;
  int t = threadIdx.x;
  cur[t] = (node0 + t < NN) ? rowptr[node0 + t] : 0;
  __syncthreads();
  int beg = rowptr[node0], end = rowptr[node1];
  for (int i = beg + t; i < end; i += 256) {
    unsigned v = packed[i];
    int pos = atomicAdd(&cur[v >> 17], 1);
    csr_src[pos] = (int)(v & 0x1FFFFu);
  }
}

// ---------------- tiled GEMM with fp16 scaled output: Ch[n,M] = half((A@W) * scale[r]) ----------------
template<int K>
__global__ __launch_bounds__(256) void k_gemmh(const float* __restrict__ A, const float* __restrict__ W,
                                               __half* __restrict__ Ch, int n, int M,
                                               const float* __restrict__ scale) {
  constexpr int AS = K + 4;
  __shared__ float As[64 * AS];
  int tid = threadIdx.x;
  int rowBase = blockIdx.x * 64;
  int colBase = blockIdx.y * 64;
  int nrows = n - rowBase; if (nrows > 64) nrows = 64;

  for (int idx = tid * 4; idx < 64 * K; idx += 1024) {
    int row = idx / K;
    int k = idx - row * K;
    float4 v = make_float4(0.f, 0.f, 0.f, 0.f);
    if (row < nrows) v = *(const float4*)(A + (size_t)(rowBase + row) * K + k);
    *(float4*)(&As[row * AS + k]) = v;
  }
  __syncthreads();

  int tx = tid & 15, ty = tid >> 4;
  int c0 = colBase + tx * 4;
  int r0 = ty * 4;
  float acc[4][4] = {{0.f}};

  for (int k = 0; k < K; ++k) {
    float4 wv = *(const float4*)(W + (size_t)k * M + c0);
    float wa[4] = {wv.x, wv.y, wv.z, wv.w};
#pragma unroll
    for (int i = 0; i < 4; ++i) {
      float a = As[(r0 + i) * AS + k];
#pragma unroll
      for (int j = 0; j < 4; ++j) acc[i][j] = fmaf(a, wa[j], acc[i][j]);
    }
  }

#pragma unroll
  for (int i = 0; i < 4; ++i) {
    int r = rowBase + r0 + i;
    if (r < n) {
      float sc = scale[r];
      __half2 p0 = __floats2half2_rn(acc[i][0] * sc, acc[i][1] * sc);
      __half2 p1 = __floats2half2_rn(acc[i][2] * sc, acc[i][3] * sc);
      __half2* cp = (__half2*)(Ch + (size_t)r * M + c0);
      cp[0] = p0;
      cp[1] = p1;
    }
  }
}

// ---------------- gather (fp16 table, 4 edges/wave in flight, 8B loads) ----------------
// h[d] = relu(dinv[d]*(hws[d] + sum_e hws[src_e]) + b)
__global__ __launch_bounds__(256) void k_gather(const __half* __restrict__ hws, const int* __restrict__ rowptr,
                                                const int* __restrict__ csr_src, const float* __restrict__ dinv,
                                                const float* __restrict__ b, float* __restrict__ h) {
  int node = blockIdx.x * 4 + (threadIdx.x >> 6);
  if (node >= NN) return;
  int lane = threadIdx.x & 63;
  int f4  = lane & 15;    // 8B segment within the 128B row (features 4*f4 .. 4*f4+3)
  int grp = lane >> 4;    // 0..3: edge subgroup
  int beg = rowptr[node], end = rowptr[node + 1];
  const uint2* hw2 = (const uint2*)hws;   // one row = 16 uint2
  float4 acc = make_float4(0.f, 0.f, 0.f, 0.f);

  for (int base = beg; base < end; base += 64) {
    int m = end - base; if (m > 64) m = 64;
    int myS = (lane < m) ? csr_src[base + lane] : 0;
    int nq = m & ~3;
    int i = 0;
#pragma unroll 4
    for (; i < nq; i += 4) {
      int s = __shfl(myS, i + grp);
      uint2 u = hw2[(size_t)s * 16 + f4];
      float2 fa = __half22float2(*(__half2*)&u.x);
      float2 fb = __half22float2(*(__half2*)&u.y);
      acc.x += fa.x; acc.y += fa.y; acc.z += fb.x; acc.w += fb.y;
    }
    if (i < m) {
      int idx = i + grp;
      int s = __shfl(myS, idx < m ? idx : 0);
      if (idx < m) {
        uint2 u = hw2[(size_t)s * 16 + f4];
        float2 fa = __half22float2(*(__half2*)&u.x);
        float2 fb = __half22float2(*(__half2*)&u.y);
        acc.x += fa.x; acc.y += fa.y; acc.z += fb.x; acc.w += fb.y;
      }
    }
  }

  // reduce across the 4 edge subgroups (lane bits 4 and 5)
  acc.x += __shfl_xor(acc.x, 16); acc.y += __shfl_xor(acc.y, 16);
  acc.z += __shfl_xor(acc.z, 16); acc.w += __shfl_xor(acc.w, 16);
  acc.x += __shfl_xor(acc.x, 32); acc.y += __shfl_xor(acc.y, 32);
  acc.z += __shfl_xor(acc.z, 32); acc.w += __shfl_xor(acc.w, 32);

  if (lane < 16) {
    uint2 u = hw2[(size_t)node * 16 + f4];          // self-loop (already dinv-scaled)
    float2 fa = __half22float2(*(__half2*)&u.x);
    float2 fb = __half22float2(*(__half2*)&u.y);
    acc.x += fa.x; acc.y += fa.y; acc.z += fb.x; acc.w += fb.y;
    float di = dinv[node];
    float4 bb = ((const float4*)b)[f4];
    float4 o;
    o.x = fmaxf(fmaf(di, acc.x, bb.x), 0.f);
    o.y = fmaxf(fmaf(di, acc.y, bb.y), 0.f);
    o.z = fmaxf(fmaf(di, acc.z, bb.z), 0.f);
    o.w = fmaxf(fmaf(di, acc.w, bb.w), 0.f);
    *(float4*)(h + (size_t)node * HD + f4 * 4) = o;
  }
}

// ---------------- transpose GRU weights: Wt[k][192] ----------------
__global__ __launch_bounds__(256) void k_transpose(const float* __restrict__ w_ih, const float* __restrict__ w_hh,
                                                   float* __restrict__ WtIH, float* __restrict__ WtHH) {
  int t = blockIdx.x * 256 + threadIdx.x;
  if (t < 192 * 64) {
    int j = t >> 6, k = t & 63;
    WtIH[k * 192 + j] = w_ih[t];
    WtHH[k * 192 + j] = w_hh[t];
  }
}

// ---------------- fused GRU: 32-node tiles (17.4KB LDS -> high occupancy) ----------------
#define GST 68   // LDS row stride (words): 16B-aligned float4 stores, conflict-free reads
__global__ __launch_bounds__(256) void k_grufused(const float* __restrict__ h, const float* __restrict__ prev,
                                                  const float* __restrict__ WtIH, const float* __restrict__ WtHH,
                                                  const float* __restrict__ bih, const float* __restrict__ bhh,
                                                  float* __restrict__ hnew) {
  __shared__ float hs[32 * GST];
  __shared__ float h0s[32 * GST];
  int tid = threadIdx.x;
  int rowBase = blockIdx.x * 32;   // NN = 3125 * 32, no tail

  for (int idx = tid * 4; idx < 32 * 64; idx += 1024) {
    int r = idx >> 6, k = idx & 63;
    float4 v = *(const float4*)(h + (size_t)(rowBase + r) * HD + k);
    float4 w = *(const float4*)(prev + (size_t)(rowBase + r) * HD + k);
    *(float4*)(&hs[r * GST + k]) = v;
    *(float4*)(&h0s[r * GST + k]) = w;
  }
  __syncthreads();

  int tx = tid & 15, ty = tid >> 4;
  int c0 = tx * 4;       // feature col within gate
  int r0 = ty * 2;       // node row within tile (2 rows/thread)
  float rr[2][4], zz[2][4];

#pragma unroll
  for (int g = 0; g < 3; ++g) {
    float gi[2][4] = {{0.f}}, gh[2][4] = {{0.f}};
    for (int k = 0; k < HD; ++k) {
      float4 wi = *(const float4*)(WtIH + k * 192 + g * 64 + c0);
      float4 wh = *(const float4*)(WtHH + k * 192 + g * 64 + c0);
      float wia[4] = {wi.x, wi.y, wi.z, wi.w};
      float wha[4] = {wh.x, wh.y, wh.z, wh.w};
#pragma unroll
      for (int i = 0; i < 2; ++i) {
        float a = hs[(r0 + i) * GST + k];
        float b0 = h0s[(r0 + i) * GST + k];
#pragma unroll
        for (int j = 0; j < 4; ++j) {
          gi[i][j] = fmaf(a, wia[j], gi[i][j]);
          gh[i][j] = fmaf(b0, wha[j], gh[i][j]);
        }
      }
    }
    float4 biv = *(const float4*)(bih + g * 64 + c0);
    float4 bhv = *(const float4*)(bhh + g * 64 + c0);
    float bia[4] = {biv.x, biv.y, biv.z, biv.w};
    float bha[4] = {bhv.x, bhv.y, bhv.z, bhv.w};
    if (g == 0) {
#pragma unroll
      for (int i = 0; i < 2; ++i)
#pragma unroll
        for (int j = 0; j < 4; ++j)
          rr[i][j] = 1.f / (1.f + expf(-(gi[i][j] + bia[j] + gh[i][j] + bha[j])));
    } else if (g == 1) {
#pragma unroll
      for (int i = 0; i < 2; ++i)
#pragma unroll
        for (int j = 0; j < 4; ++j)
          zz[i][j] = 1.f / (1.f + expf(-(gi[i][j] + bia[j] + gh[i][j] + bha[j])));
    } else {
#pragma unroll
      for (int i = 0; i < 2; ++i) {
        int r = rowBase + r0 + i;
        float o[4];
#pragma unroll
        for (int j = 0; j < 4; ++j) {
          float nc = tanhf(gi[i][j] + bia[j] + rr[i][j] * (gh[i][j] + bha[j]));
          float h0v = h0s[(r0 + i) * GST + c0 + j];
          o[j] = (1.f - zz[i][j]) * nc + zz[i][j] * h0v;
        }
        *(float4*)(hnew + (size_t)r * HD + c0) = make_float4(o[0], o[1], o[2], o[3]);
      }
    }
  }
}

// ---------------- readout ----------------
__global__ __launch_bounds__(256) void k_readout(const float* __restrict__ hnew, const float* __restrict__ Wp,
                                                 const float* __restrict__ bp, float* __restrict__ out) {
  int t = blockIdx.x * 256 + threadIdx.x;
  if (t >= NN * TOUT) return;
  int col = t & 15;
  int i = t >> 4;
  const float* hr = hnew + (size_t)i * HD;
  float acc = bp[col];
#pragma unroll
  for (int k = 0; k < HD; ++k) acc = fmaf(hr[k], Wp[k * TOUT + col], acc);
  out[t] = acc;
}

extern "C" void kernel_launch(void* const* d_in, const int* in_sizes, int n_in,
                              void* d_out, int out_size, void* d_ws, size_t ws_size,
                              hipStream_t stream) {
  const float* x    = (const float*)d_in[0];
  const int*   ei   = (const int*)d_in[1];
  const float* prev = (const float*)d_in[2];
  const float* W1   = (const float*)d_in[3];
  const float* b1   = (const float*)d_in[4];
  const float* W2   = (const float*)d_in[5];
  const float* b2   = (const float*)d_in[6];
  const float* w_ih = (const float*)d_in[7];
  const float* w_hh = (const float*)d_in[8];
  const float* b_ih = (const float*)d_in[9];
  const float* b_hh = (const float*)d_in[10];
  const float* Wp   = (const float*)d_in[11];
  const float* bp   = (const float*)d_in[12];

  float* out  = (float*)d_out;                 // [NN,16]
  float* hnew = out + (size_t)NN * TOUT;       // [NN,64]

  char* ws = (char*)d_ws;
  float*    dinv    = (float*)(ws + 0);                    // 400,000
  unsigned* degI    = (unsigned*)(ws + 400000);            // 400,000
  int*      rowptr  = (int*)(ws + 800000);                 // 400,064
  int*      bcur    = (int*)(ws + 1200064);                // 1,564
  unsigned* blkSum  = (unsigned*)(ws + 1208064);           // 4,160
  int*      csr_src = (int*)(ws + 1212224);                // 12,800,000
  __half*   hwsH    = (__half*)(ws + 14012224);            // 12,800,000
  float*    bufB    = (float*)(ws + 26812224);             // 25,600,000 (packed u32 alias)
  float*    bufC    = (float*)(ws + 52412224);             // 25,600,000
  float*    WtIH    = (float*)(ws + 78012224);             // 49,152
  float*    WtHH    = (float*)(ws + 78061376);             // 49,152
  unsigned* packed  = (unsigned*)bufB;

  const int* srcA = ei;
  const int* dstA = ei + NE;

  // ---- degree / norm / CSR build ----
  hipMemsetAsync(degI, 0, NN * sizeof(unsigned), stream);
  k_deg<<<(NE + 255) / 256, 256, 0, stream>>>(dstA, degI);
  k_dinv<<<(NN + 255) / 256, 256, 0, stream>>>(degI, dinv);
  k_scan_local<<<NB_SCAN, 256, 0, stream>>>(degI, rowptr, blkSum);
  k_scan_block<<<1, 512, 0, stream>>>(blkSum);
  k_scan_add<<<NB_SCAN, 256, 0, stream>>>(rowptr, blkSum, bcur);
  k_p1<<<(NE + EPB - 1) / EPB, 256, 0, stream>>>(srcA, dstA, bcur, packed);
  k_p2<<<NBUK, 256, 0, stream>>>(packed, rowptr, csr_src);

  // ---- GCN layer 1 ----
  k_gemmh<FIN><<<dim3((NN + 63) / 64, 1), 256, 0, stream>>>(x, W1, hwsH, NN, HD, dinv);
  k_gather<<<(NN + 3) / 4, 256, 0, stream>>>(hwsH, rowptr, csr_src, dinv, b1, bufC);

  // ---- GCN layer 2 ----
  k_gemmh<HD><<<dim3((NN + 63) / 64, 1), 256, 0, stream>>>(bufC, W2, hwsH, NN, HD, dinv);
  k_gather<<<(NN + 3) / 4, 256, 0, stream>>>(hwsH, rowptr, csr_src, dinv, b2, bufC);

  // ---- fused GRU ----
  k_transpose<<<(192 * 64 + 255) / 256, 256, 0, stream>>>(w_ih, w_hh, WtIH, WtHH);
  k_grufused<<<(NN + 31) / 32, 256, 0, stream>>>(bufC, prev, WtIH, WtHH, b_ih, b_hh, hnew);

  // ---- readout ----
  k_readout<<<(NN * TOUT + 255) / 256, 256, 0, stream>>>(hnew, Wp, bp, out);
}

// Round 7
// 562.704 us; speedup vs baseline: 1.1249x; 1.1249x over previous
//
#include <hip/hip_runtime.h>
#include <hip/hip_fp16.h>
#include <math.h>

#define NN 100000
#define NE 3200000
#define FIN 128
#define HD 64
#define TOUT 16
#define NB_SCAN ((NN + 255) / 256)   // 391
#define BSH 8                        // 256 nodes per bucket
#define NBUK ((NN + 255) / 256)      // 391 buckets
#define EPB 8192                     // edges per P1 block

// ---------------- degree ----------------
__global__ __launch_bounds__(256) void k_deg(const int* __restrict__ dst, unsigned* __restrict__ deg) {
  int e = blockIdx.x * 256 + threadIdx.x;
  if (e < NE) atomicAdd(&deg[dst[e]], 1u);
}

__global__ __launch_bounds__(256) void k_dinv(const unsigned* __restrict__ deg, float* __restrict__ dinv) {
  int i = blockIdx.x * 256 + threadIdx.x;
  if (i < NN) dinv[i] = 1.0f / sqrtf((float)deg[i] + 1.0f);  // +1 self-loop
}

// ---------------- exclusive scan (3 phases) ----------------
__global__ __launch_bounds__(256) void k_scan_local(const unsigned* __restrict__ deg,
                                                    int* __restrict__ rowptr,
                                                    unsigned* __restrict__ blockSum) {
  __shared__ unsigned s[256];
  int t = threadIdx.x, i = blockIdx.x * 256 + t;
  unsigned v = (i < NN) ? deg[i] : 0u;
  s[t] = v;
  __syncthreads();
  for (int off = 1; off < 256; off <<= 1) {
    unsigned y = (t >= off) ? s[t - off] : 0u;
    __syncthreads();
    s[t] += y;
    __syncthreads();
  }
  if (i < NN) rowptr[i] = (int)(s[t] - v);
  if (t == 255) blockSum[blockIdx.x] = s[255];
}

__global__ __launch_bounds__(512) void k_scan_block(unsigned* __restrict__ blockSum) {
  __shared__ unsigned s[512];
  int t = threadIdx.x;
  unsigned v = (t < NB_SCAN) ? blockSum[t] : 0u;
  s[t] = v;
  __syncthreads();
  for (int off = 1; off < 512; off <<= 1) {
    unsigned y = (t >= off) ? s[t - off] : 0u;
    __syncthreads();
    s[t] += y;
    __syncthreads();
  }
  if (t < NB_SCAN) blockSum[t] = s[t] - v;
}

__global__ __launch_bounds__(256) void k_scan_add(int* __restrict__ rowptr, const unsigned* __restrict__ blockSum,
                                                  int* __restrict__ bcur) {
  int i = blockIdx.x * 256 + threadIdx.x;
  if (i < NN) {
    int r = rowptr[i] + (int)blockSum[i >> 8];
    rowptr[i] = r;
    if ((i & 255) == 0) bcur[i >> BSH] = r;
  }
  if (i == 0) rowptr[NN] = NE;
}

// ---------------- P1: block-local histogram + contiguous run reservation ----------------
__global__ __launch_bounds__(256) void k_p1(const int* __restrict__ src, const int* __restrict__ dst,
                                            int* __restrict__ bcur, unsigned* __restrict__ packed) {
  __shared__ int hist[NBUK];
  __shared__ int base[NBUK];
  int t = threadIdx.x;
  int e0 = blockIdx.x * EPB;
  int e1 = e0 + EPB; if (e1 > NE) e1 = NE;

  for (int i = t; i < NBUK; i += 256) hist[i] = 0;
  __syncthreads();
  for (int e = e0 + t; e < e1; e += 256) atomicAdd(&hist[dst[e] >> BSH], 1);
  __syncthreads();
  for (int i = t; i < NBUK; i += 256) {
    int c = hist[i];
    base[i] = c ? atomicAdd(&bcur[i], c) : 0;
    hist[i] = 0;
  }
  __syncthreads();
  for (int e = e0 + t; e < e1; e += 256) {
    int d = dst[e];
    int b = d >> BSH;
    int p = base[b] + atomicAdd(&hist[b], 1);
    packed[p] = ((unsigned)(d & 255) << 17) | (unsigned)src[e];
  }
}

// ---------------- P2: node-exact CSR within each bucket ----------------
__global__ __launch_bounds__(256) void k_p2(const unsigned* __restrict__ packed, const int* __restrict__ rowptr,
                                            int* __restrict__ csr_src) {
  __shared__ int cur[256];
  int b = blockIdx.x;
  int node0 = b << BSH;
  int node1 = node0 + 256; if (node1 > NN) node1 = NN;
  int t = threadIdx.x;
  cur[t] = (node0 + t < NN) ? rowptr[node0 + t] : 0;
  __syncthreads();
  int beg = rowptr[node0], end = rowptr[node1];
  for (int i = beg + t; i < end; i += 256) {
    unsigned v = packed[i];
    int pos = atomicAdd(&cur[v >> 17], 1);
    csr_src[pos] = (int)(v & 0x1FFFFu);
  }
}

// ---------------- tiled GEMM with fp16 scaled output: Ch[n,M] = half((A@W) * scale[r]) ----------------
template<int K>
__global__ __launch_bounds__(256) void k_gemmh(const float* __restrict__ A, const float* __restrict__ W,
                                               __half* __restrict__ Ch, int n, int M,
                                               const float* __restrict__ scale) {
  constexpr int AS = K + 4;
  __shared__ float As[64 * AS];
  int tid = threadIdx.x;
  int rowBase = blockIdx.x * 64;
  int colBase = blockIdx.y * 64;
  int nrows = n - rowBase; if (nrows > 64) nrows = 64;

  for (int idx = tid * 4; idx < 64 * K; idx += 1024) {
    int row = idx / K;
    int k = idx - row * K;
    float4 v = make_float4(0.f, 0.f, 0.f, 0.f);
    if (row < nrows) v = *(const float4*)(A + (size_t)(rowBase + row) * K + k);
    *(float4*)(&As[row * AS + k]) = v;
  }
  __syncthreads();

  int tx = tid & 15, ty = tid >> 4;
  int c0 = colBase + tx * 4;
  int r0 = ty * 4;
  float acc[4][4] = {{0.f}};

  for (int k = 0; k < K; ++k) {
    float4 wv = *(const float4*)(W + (size_t)k * M + c0);
    float wa[4] = {wv.x, wv.y, wv.z, wv.w};
#pragma unroll
    for (int i = 0; i < 4; ++i) {
      float a = As[(r0 + i) * AS + k];
#pragma unroll
      for (int j = 0; j < 4; ++j) acc[i][j] = fmaf(a, wa[j], acc[i][j]);
    }
  }

#pragma unroll
  for (int i = 0; i < 4; ++i) {
    int r = rowBase + r0 + i;
    if (r < n) {
      float sc = scale[r];
      __half2 p0 = __floats2half2_rn(acc[i][0] * sc, acc[i][1] * sc);
      __half2 p1 = __floats2half2_rn(acc[i][2] * sc, acc[i][3] * sc);
      __half2* cp = (__half2*)(Ch + (size_t)r * M + c0);
      cp[0] = p0;
      cp[1] = p1;
    }
  }
}

// ---------------- gather (fp16 table, 4 edges/wave in flight, 8B loads) ----------------
__global__ __launch_bounds__(256) void k_gather(const __half* __restrict__ hws, const int* __restrict__ rowptr,
                                                const int* __restrict__ csr_src, const float* __restrict__ dinv,
                                                const float* __restrict__ b, float* __restrict__ h) {
  int node = blockIdx.x * 4 + (threadIdx.x >> 6);
  if (node >= NN) return;
  int lane = threadIdx.x & 63;
  int f4  = lane & 15;
  int grp = lane >> 4;
  int beg = rowptr[node], end = rowptr[node + 1];
  const uint2* hw2 = (const uint2*)hws;
  float4 acc = make_float4(0.f, 0.f, 0.f, 0.f);

  for (int base = beg; base < end; base += 64) {
    int m = end - base; if (m > 64) m = 64;
    int myS = (lane < m) ? csr_src[base + lane] : 0;
    int nq = m & ~3;
    int i = 0;
#pragma unroll 4
    for (; i < nq; i += 4) {
      int s = __shfl(myS, i + grp);
      uint2 u = hw2[(size_t)s * 16 + f4];
      float2 fa = __half22float2(*(__half2*)&u.x);
      float2 fb = __half22float2(*(__half2*)&u.y);
      acc.x += fa.x; acc.y += fa.y; acc.z += fb.x; acc.w += fb.y;
    }
    if (i < m) {
      int idx = i + grp;
      int s = __shfl(myS, idx < m ? idx : 0);
      if (idx < m) {
        uint2 u = hw2[(size_t)s * 16 + f4];
        float2 fa = __half22float2(*(__half2*)&u.x);
        float2 fb = __half22float2(*(__half2*)&u.y);
        acc.x += fa.x; acc.y += fa.y; acc.z += fb.x; acc.w += fb.y;
      }
    }
  }

  acc.x += __shfl_xor(acc.x, 16); acc.y += __shfl_xor(acc.y, 16);
  acc.z += __shfl_xor(acc.z, 16); acc.w += __shfl_xor(acc.w, 16);
  acc.x += __shfl_xor(acc.x, 32); acc.y += __shfl_xor(acc.y, 32);
  acc.z += __shfl_xor(acc.z, 32); acc.w += __shfl_xor(acc.w, 32);

  if (lane < 16) {
    uint2 u = hw2[(size_t)node * 16 + f4];
    float2 fa = __half22float2(*(__half2*)&u.x);
    float2 fb = __half22float2(*(__half2*)&u.y);
    acc.x += fa.x; acc.y += fa.y; acc.z += fb.x; acc.w += fb.y;
    float di = dinv[node];
    float4 bb = ((const float4*)b)[f4];
    float4 o;
    o.x = fmaxf(fmaf(di, acc.x, bb.x), 0.f);
    o.y = fmaxf(fmaf(di, acc.y, bb.y), 0.f);
    o.z = fmaxf(fmaf(di, acc.z, bb.z), 0.f);
    o.w = fmaxf(fmaf(di, acc.w, bb.w), 0.f);
    *(float4*)(h + (size_t)node * HD + f4 * 4) = o;
  }
}

// ---------------- prep: Wcat[k][192] = k<64 ? w_ih[:,k].T : w_hh[:,k-64].T ----------------
__global__ __launch_bounds__(256) void k_prep(const float* __restrict__ w_ih, const float* __restrict__ w_hh,
                                              float* __restrict__ Wcat) {
  int t = blockIdx.x * 256 + threadIdx.x;
  if (t >= 128 * 192) return;
  int k = t / 192, c = t - k * 192;
  Wcat[t] = (k < 64) ? w_ih[c * 64 + k] : w_hh[c * 64 + (k - 64)];
}

// ---------------- fused GRU as K=128 GEMM + gate epilogue + readout ----------------
// A-tile: 64 rows x 128 cols (h | h0), LDS stride 132. acc: r,z combined over K=128;
// n gate split into input part (k<64) and hidden part (k>=64).
#define AST 132
__global__ __launch_bounds__(256) void k_grufused(const float* __restrict__ h, const float* __restrict__ prev,
                                                  const float* __restrict__ Wcat,
                                                  const float* __restrict__ bih, const float* __restrict__ bhh,
                                                  const float* __restrict__ Wp, const float* __restrict__ bp,
                                                  float* __restrict__ hnew, float* __restrict__ out) {
  __shared__ float As[64 * AST];
  int tid = threadIdx.x;
  int rowBase = blockIdx.x * 64;
  int nrows = NN - rowBase; if (nrows > 64) nrows = 64;

  for (int idx = tid * 4; idx < 64 * 64; idx += 1024) {
    int r = idx >> 6, k = idx & 63;
    float4 v = make_float4(0.f, 0.f, 0.f, 0.f);
    float4 w = make_float4(0.f, 0.f, 0.f, 0.f);
    if (r < nrows) {
      v = *(const float4*)(h + (size_t)(rowBase + r) * HD + k);
      w = *(const float4*)(prev + (size_t)(rowBase + r) * HD + k);
    }
    *(float4*)(&As[r * AST + k]) = v;
    *(float4*)(&As[r * AST + 64 + k]) = w;
  }
  __syncthreads();

  int tx = tid & 15, ty = tid >> 4;
  int c0 = tx * 4;       // feature col within each gate
  int r0 = ty * 4;       // node row within tile
  float aR[4][4] = {{0.f}}, aZ[4][4] = {{0.f}}, aNi[4][4] = {{0.f}}, aNh[4][4] = {{0.f}};

  // phase 1: k in [0,64)  -> A = h; n-gate into aNi
  for (int k = 0; k < 64; ++k) {
    float4 wr = *(const float4*)(Wcat + k * 192 + c0);
    float4 wz = *(const float4*)(Wcat + k * 192 + 64 + c0);
    float4 wn = *(const float4*)(Wcat + k * 192 + 128 + c0);
    float wra[4] = {wr.x, wr.y, wr.z, wr.w};
    float wza[4] = {wz.x, wz.y, wz.z, wz.w};
    float wna[4] = {wn.x, wn.y, wn.z, wn.w};
#pragma unroll
    for (int i = 0; i < 4; ++i) {
      float a = As[(r0 + i) * AST + k];
#pragma unroll
      for (int j = 0; j < 4; ++j) {
        aR[i][j]  = fmaf(a, wra[j], aR[i][j]);
        aZ[i][j]  = fmaf(a, wza[j], aZ[i][j]);
        aNi[i][j] = fmaf(a, wna[j], aNi[i][j]);
      }
    }
  }
  // phase 2: k in [64,128) -> A = h0; n-gate into aNh
  for (int k = 64; k < 128; ++k) {
    float4 wr = *(const float4*)(Wcat + k * 192 + c0);
    float4 wz = *(const float4*)(Wcat + k * 192 + 64 + c0);
    float4 wn = *(const float4*)(Wcat + k * 192 + 128 + c0);
    float wra[4] = {wr.x, wr.y, wr.z, wr.w};
    float wza[4] = {wz.x, wz.y, wz.z, wz.w};
    float wna[4] = {wn.x, wn.y, wn.z, wn.w};
#pragma unroll
    for (int i = 0; i < 4; ++i) {
      float a = As[(r0 + i) * AST + k];
#pragma unroll
      for (int j = 0; j < 4; ++j) {
        aR[i][j]  = fmaf(a, wra[j], aR[i][j]);
        aZ[i][j]  = fmaf(a, wza[j], aZ[i][j]);
        aNh[i][j] = fmaf(a, wna[j], aNh[i][j]);
      }
    }
  }

  float4 birv = *(const float4*)(bih + c0);
  float4 bhrv = *(const float4*)(bhh + c0);
  float4 bizv = *(const float4*)(bih + 64 + c0);
  float4 bhzv = *(const float4*)(bhh + 64 + c0);
  float4 binv = *(const float4*)(bih + 128 + c0);
  float4 bhnv = *(const float4*)(bhh + 128 + c0);
  float bir[4] = {birv.x, birv.y, birv.z, birv.w};
  float bhr[4] = {bhrv.x, bhrv.y, bhrv.z, bhrv.w};
  float biz[4] = {bizv.x, bizv.y, bizv.z, bizv.w};
  float bhz[4] = {bhzv.x, bhzv.y, bhzv.z, bhzv.w};
  float bin[4] = {binv.x, binv.y, binv.z, binv.w};
  float bhn[4] = {bhnv.x, bhnv.y, bhnv.z, bhnv.w};

  float oo[4][4];
#pragma unroll
  for (int i = 0; i < 4; ++i) {
    int r = rowBase + r0 + i;
#pragma unroll
    for (int j = 0; j < 4; ++j) {
      float rg = 1.f / (1.f + expf(-(aR[i][j] + bir[j] + bhr[j])));
      float zg = 1.f / (1.f + expf(-(aZ[i][j] + biz[j] + bhz[j])));
      float nc = tanhf(aNi[i][j] + bin[j] + rg * (aNh[i][j] + bhn[j]));
      float h0v = As[(r0 + i) * AST + 64 + c0 + j];
      oo[i][j] = (1.f - zg) * nc + zg * h0v;
    }
    if (r < NN)
      *(float4*)(hnew + (size_t)r * HD + c0) = make_float4(oo[i][0], oo[i][1], oo[i][2], oo[i][3]);
  }

  // ---- fused readout: stash hnew tile into LDS, compute out = hnew@Wp + bp ----
  __syncthreads();   // all phase/epilogue reads of As done
#pragma unroll
  for (int i = 0; i < 4; ++i)
    *(float4*)(&As[(r0 + i) * AST + c0]) = make_float4(oo[i][0], oo[i][1], oo[i][2], oo[i][3]);
  __syncthreads();

  int orow = tid >> 2;            // 0..63
  int oc0 = (tid & 3) * 4;        // 0,4,8,12
  if (rowBase + orow < NN) {
    float4 bpv = *(const float4*)(bp + oc0);
    float racc[4] = {bpv.x, bpv.y, bpv.z, bpv.w};
    for (int k = 0; k < HD; ++k) {
      float hv = As[orow * AST + k];
      float4 wp = *(const float4*)(Wp + k * TOUT + oc0);
      racc[0] = fmaf(hv, wp.x, racc[0]);
      racc[1] = fmaf(hv, wp.y, racc[1]);
      racc[2] = fmaf(hv, wp.z, racc[2]);
      racc[3] = fmaf(hv, wp.w, racc[3]);
    }
    *(float4*)(out + (size_t)(rowBase + orow) * TOUT + oc0) = make_float4(racc[0], racc[1], racc[2], racc[3]);
  }
}

extern "C" void kernel_launch(void* const* d_in, const int* in_sizes, int n_in,
                              void* d_out, int out_size, void* d_ws, size_t ws_size,
                              hipStream_t stream) {
  const float* x    = (const float*)d_in[0];
  const int*   ei   = (const int*)d_in[1];
  const float* prev = (const float*)d_in[2];
  const float* W1   = (const float*)d_in[3];
  const float* b1   = (const float*)d_in[4];
  const float* W2   = (const float*)d_in[5];
  const float* b2   = (const float*)d_in[6];
  const float* w_ih = (const float*)d_in[7];
  const float* w_hh = (const float*)d_in[8];
  const float* b_ih = (const float*)d_in[9];
  const float* b_hh = (const float*)d_in[10];
  const float* Wp   = (const float*)d_in[11];
  const float* bp   = (const float*)d_in[12];

  float* out  = (float*)d_out;                 // [NN,16]
  float* hnew = out + (size_t)NN * TOUT;       // [NN,64]

  char* ws = (char*)d_ws;
  float*    dinv    = (float*)(ws + 0);                    // 400,000
  unsigned* degI    = (unsigned*)(ws + 400000);            // 400,000
  int*      rowptr  = (int*)(ws + 800000);                 // 400,064
  int*      bcur    = (int*)(ws + 1200064);                // 1,564
  unsigned* blkSum  = (unsigned*)(ws + 1208064);           // 4,160
  int*      csr_src = (int*)(ws + 1212224);                // 12,800,000
  __half*   hwsH    = (__half*)(ws + 14012224);            // 12,800,000
  float*    bufB    = (float*)(ws + 26812224);             // 25,600,000 (packed u32 alias)
  float*    bufC    = (float*)(ws + 52412224);             // 25,600,000
  float*    Wcat    = (float*)(ws + 78012224);             // 98,304
  unsigned* packed  = (unsigned*)bufB;

  const int* srcA = ei;
  const int* dstA = ei + NE;

  // ---- degree / norm / CSR build ----
  hipMemsetAsync(degI, 0, NN * sizeof(unsigned), stream);
  k_deg<<<(NE + 255) / 256, 256, 0, stream>>>(dstA, degI);
  k_dinv<<<(NN + 255) / 256, 256, 0, stream>>>(degI, dinv);
  k_scan_local<<<NB_SCAN, 256, 0, stream>>>(degI, rowptr, blkSum);
  k_scan_block<<<1, 512, 0, stream>>>(blkSum);
  k_scan_add<<<NB_SCAN, 256, 0, stream>>>(rowptr, blkSum, bcur);
  k_p1<<<(NE + EPB - 1) / EPB, 256, 0, stream>>>(srcA, dstA, bcur, packed);
  k_p2<<<NBUK, 256, 0, stream>>>(packed, rowptr, csr_src);

  // ---- GCN layer 1 ----
  k_gemmh<FIN><<<dim3((NN + 63) / 64, 1), 256, 0, stream>>>(x, W1, hwsH, NN, HD, dinv);
  k_gather<<<(NN + 3) / 4, 256, 0, stream>>>(hwsH, rowptr, csr_src, dinv, b1, bufC);

  // ---- GCN layer 2 ----
  k_gemmh<HD><<<dim3((NN + 63) / 64, 1), 256, 0, stream>>>(bufC, W2, hwsH, NN, HD, dinv);
  k_gather<<<(NN + 3) / 4, 256, 0, stream>>>(hwsH, rowptr, csr_src, dinv, b2, bufC);

  // ---- fused GRU (K=128 GEMM + gates + readout) ----
  k_prep<<<(128 * 192 + 255) / 256, 256, 0, stream>>>(w_ih, w_hh, Wcat);
  k_grufused<<<(NN + 63) / 64, 256, 0, stream>>>(bufC, prev, Wcat, b_ih, b_hh, Wp, bp, hnew, out);
}

// Round 8
// 431.791 us; speedup vs baseline: 1.4659x; 1.3032x over previous
//
#include <hip/hip_runtime.h>
#include <hip/hip_fp16.h>
#include <math.h>

#define NN 100000
#define NE 3200000
#define FIN 128
#define HD 64
#define TOUT 16
#define BSH 8                        // 256 nodes per bucket
#define NBUK ((NN + 255) / 256)      // 391 buckets
#define EPB 8192                     // edges per P1 block
#define CAP 12288                    // slots per bucket (mean 8192, ~45 sigma headroom)

// ---------------- init bucket cursors to fixed-capacity region starts ----------------
__global__ __launch_bounds__(256) void k_init(int* __restrict__ bcur) {
  int t = blockIdx.x * 256 + threadIdx.x;
  if (t < NBUK) bcur[t] = t * CAP;
}

// ---------------- P1: block-local histogram + contiguous run reservation (fixed-cap buckets) ----------------
__global__ __launch_bounds__(256) void k_p1(const int* __restrict__ src, const int* __restrict__ dst,
                                            int* __restrict__ bcur, unsigned* __restrict__ packed) {
  __shared__ int hist[NBUK];
  __shared__ int base[NBUK];
  int t = threadIdx.x;
  int e0 = blockIdx.x * EPB;
  int e1 = e0 + EPB; if (e1 > NE) e1 = NE;

  for (int i = t; i < NBUK; i += 256) hist[i] = 0;
  __syncthreads();
  for (int e = e0 + t; e < e1; e += 256) atomicAdd(&hist[dst[e] >> BSH], 1);
  __syncthreads();
  for (int i = t; i < NBUK; i += 256) {
    int c = hist[i];
    base[i] = c ? atomicAdd(&bcur[i], c) : 0;
    hist[i] = 0;
  }
  __syncthreads();
  for (int e = e0 + t; e < e1; e += 256) {
    int d = dst[e];
    int b = d >> BSH;
    int p = base[b] + atomicAdd(&hist[b], 1);
    packed[p] = ((unsigned)(d & 255) << 17) | (unsigned)src[e];
  }
}

// ---------------- scan bucket totals -> global bucket bases ----------------
__global__ __launch_bounds__(512) void k_scanb(const int* __restrict__ bcur, int* __restrict__ bktBase,
                                               int* __restrict__ rowptr) {
  __shared__ int s[512];
  int t = threadIdx.x;
  int v = (t < NBUK) ? (bcur[t] - t * CAP) : 0;
  s[t] = v;
  __syncthreads();
  for (int off = 1; off < 512; off <<= 1) {
    int y = (t >= off) ? s[t - off] : 0;
    __syncthreads();
    s[t] += y;
    __syncthreads();
  }
  if (t < NBUK) bktBase[t] = s[t] - v;
  if (t == 0) rowptr[NN] = NE;
}

// ---------------- P2: per-bucket degree histogram + local scan + rowptr/dinv + CSR place ----------------
__global__ __launch_bounds__(256) void k_p2big(const unsigned* __restrict__ packed, const int* __restrict__ bcur,
                                               const int* __restrict__ bktBase, int* __restrict__ rowptr,
                                               float* __restrict__ dinv, int* __restrict__ csr_src) {
  __shared__ int degl[256];
  __shared__ int sc[256];
  __shared__ int cur[256];
  int b = blockIdx.x, t = threadIdx.x;
  int pbase = b * CAP;
  int cnt = bcur[b] - pbase;

  degl[t] = 0;
  __syncthreads();
  for (int i = t; i < cnt; i += 256) {
    unsigned v = packed[pbase + i];
    atomicAdd(&degl[v >> 17], 1);
  }
  __syncthreads();
  int dv = degl[t];
  sc[t] = dv;
  __syncthreads();
  for (int off = 1; off < 256; off <<= 1) {
    int y = (t >= off) ? sc[t - off] : 0;
    __syncthreads();
    sc[t] += y;
    __syncthreads();
  }
  int gpos = bktBase[b] + (sc[t] - dv);
  int node = (b << BSH) + t;
  if (node < NN) {
    rowptr[node] = gpos;
    dinv[node] = 1.0f / sqrtf((float)dv + 1.0f);   // +1 self-loop
  }
  cur[t] = gpos;
  __syncthreads();
  for (int i = t; i < cnt; i += 256) {
    unsigned pv = packed[pbase + i];
    int pos = atomicAdd(&cur[pv >> 17], 1);
    csr_src[pos] = (int)(pv & 0x1FFFFu);
  }
}

// ---------------- tiled GEMM with fp16 scaled output: Ch[n,M] = half((A@W) * scale[r]) ----------------
template<int K>
__global__ __launch_bounds__(256) void k_gemmh(const float* __restrict__ A, const float* __restrict__ W,
                                               __half* __restrict__ Ch, int n, int M,
                                               const float* __restrict__ scale) {
  constexpr int AS = K + 4;
  __shared__ float As[64 * AS];
  int tid = threadIdx.x;
  int rowBase = blockIdx.x * 64;
  int colBase = blockIdx.y * 64;
  int nrows = n - rowBase; if (nrows > 64) nrows = 64;

  for (int idx = tid * 4; idx < 64 * K; idx += 1024) {
    int row = idx / K;
    int k = idx - row * K;
    float4 v = make_float4(0.f, 0.f, 0.f, 0.f);
    if (row < nrows) v = *(const float4*)(A + (size_t)(rowBase + row) * K + k);
    *(float4*)(&As[row * AS + k]) = v;
  }
  __syncthreads();

  int tx = tid & 15, ty = tid >> 4;
  int c0 = colBase + tx * 4;
  int r0 = ty * 4;
  float acc[4][4] = {{0.f}};

  for (int k = 0; k < K; ++k) {
    float4 wv = *(const float4*)(W + (size_t)k * M + c0);
    float wa[4] = {wv.x, wv.y, wv.z, wv.w};
#pragma unroll
    for (int i = 0; i < 4; ++i) {
      float a = As[(r0 + i) * AS + k];
#pragma unroll
      for (int j = 0; j < 4; ++j) acc[i][j] = fmaf(a, wa[j], acc[i][j]);
    }
  }

#pragma unroll
  for (int i = 0; i < 4; ++i) {
    int r = rowBase + r0 + i;
    if (r < n) {
      float sc = scale[r];
      __half2 p0 = __floats2half2_rn(acc[i][0] * sc, acc[i][1] * sc);
      __half2 p1 = __floats2half2_rn(acc[i][2] * sc, acc[i][3] * sc);
      __half2* cp = (__half2*)(Ch + (size_t)r * M + c0);
      cp[0] = p0;
      cp[1] = p1;
    }
  }
}

// ---------------- gather (fp16 table, 4 edges/wave in flight, 8B loads) ----------------
__global__ __launch_bounds__(256) void k_gather(const __half* __restrict__ hws, const int* __restrict__ rowptr,
                                                const int* __restrict__ csr_src, const float* __restrict__ dinv,
                                                const float* __restrict__ b, float* __restrict__ h) {
  int node = blockIdx.x * 4 + (threadIdx.x >> 6);
  if (node >= NN) return;
  int lane = threadIdx.x & 63;
  int f4  = lane & 15;
  int grp = lane >> 4;
  int beg = rowptr[node], end = rowptr[node + 1];
  const uint2* hw2 = (const uint2*)hws;
  float4 acc = make_float4(0.f, 0.f, 0.f, 0.f);

  for (int base = beg; base < end; base += 64) {
    int m = end - base; if (m > 64) m = 64;
    int myS = (lane < m) ? csr_src[base + lane] : 0;
    int nq = m & ~3;
    int i = 0;
#pragma unroll 4
    for (; i < nq; i += 4) {
      int s = __shfl(myS, i + grp);
      uint2 u = hw2[(size_t)s * 16 + f4];
      float2 fa = __half22float2(*(__half2*)&u.x);
      float2 fb = __half22float2(*(__half2*)&u.y);
      acc.x += fa.x; acc.y += fa.y; acc.z += fb.x; acc.w += fb.y;
    }
    if (i < m) {
      int idx = i + grp;
      int s = __shfl(myS, idx < m ? idx : 0);
      if (idx < m) {
        uint2 u = hw2[(size_t)s * 16 + f4];
        float2 fa = __half22float2(*(__half2*)&u.x);
        float2 fb = __half22float2(*(__half2*)&u.y);
        acc.x += fa.x; acc.y += fa.y; acc.z += fb.x; acc.w += fb.y;
      }
    }
  }

  acc.x += __shfl_xor(acc.x, 16); acc.y += __shfl_xor(acc.y, 16);
  acc.z += __shfl_xor(acc.z, 16); acc.w += __shfl_xor(acc.w, 16);
  acc.x += __shfl_xor(acc.x, 32); acc.y += __shfl_xor(acc.y, 32);
  acc.z += __shfl_xor(acc.z, 32); acc.w += __shfl_xor(acc.w, 32);

  if (lane < 16) {
    uint2 u = hw2[(size_t)node * 16 + f4];
    float2 fa = __half22float2(*(__half2*)&u.x);
    float2 fb = __half22float2(*(__half2*)&u.y);
    acc.x += fa.x; acc.y += fa.y; acc.z += fb.x; acc.w += fb.y;
    float di = dinv[node];
    float4 bb = ((const float4*)b)[f4];
    float4 o;
    o.x = fmaxf(fmaf(di, acc.x, bb.x), 0.f);
    o.y = fmaxf(fmaf(di, acc.y, bb.y), 0.f);
    o.z = fmaxf(fmaf(di, acc.z, bb.z), 0.f);
    o.w = fmaxf(fmaf(di, acc.w, bb.w), 0.f);
    *(float4*)(h + (size_t)node * HD + f4 * 4) = o;
  }
}

// ---------------- prep: Wcat[k][192] = k<64 ? w_ih[:,k].T : w_hh[:,k-64].T ----------------
__global__ __launch_bounds__(256) void k_prep(const float* __restrict__ w_ih, const float* __restrict__ w_hh,
                                              float* __restrict__ Wcat) {
  int t = blockIdx.x * 256 + threadIdx.x;
  if (t >= 128 * 192) return;
  int k = t / 192, c = t - k * 192;
  Wcat[t] = (k < 64) ? w_ih[c * 64 + k] : w_hh[c * 64 + (k - 64)];
}

// ---------------- fused GRU as K=128 GEMM + gate epilogue + readout ----------------
#define AST 132
__global__ __launch_bounds__(256) void k_grufused(const float* __restrict__ h, const float* __restrict__ prev,
                                                  const float* __restrict__ Wcat,
                                                  const float* __restrict__ bih, const float* __restrict__ bhh,
                                                  const float* __restrict__ Wp, const float* __restrict__ bp,
                                                  float* __restrict__ hnew, float* __restrict__ out) {
  __shared__ float As[64 * AST];
  int tid = threadIdx.x;
  int rowBase = blockIdx.x * 64;
  int nrows = NN - rowBase; if (nrows > 64) nrows = 64;

  for (int idx = tid * 4; idx < 64 * 64; idx += 1024) {
    int r = idx >> 6, k = idx & 63;
    float4 v = make_float4(0.f, 0.f, 0.f, 0.f);
    float4 w = make_float4(0.f, 0.f, 0.f, 0.f);
    if (r < nrows) {
      v = *(const float4*)(h + (size_t)(rowBase + r) * HD + k);
      w = *(const float4*)(prev + (size_t)(rowBase + r) * HD + k);
    }
    *(float4*)(&As[r * AST + k]) = v;
    *(float4*)(&As[r * AST + 64 + k]) = w;
  }
  __syncthreads();

  int tx = tid & 15, ty = tid >> 4;
  int c0 = tx * 4;
  int r0 = ty * 4;
  float aR[4][4] = {{0.f}}, aZ[4][4] = {{0.f}}, aNi[4][4] = {{0.f}}, aNh[4][4] = {{0.f}};

  for (int k = 0; k < 64; ++k) {
    float4 wr = *(const float4*)(Wcat + k * 192 + c0);
    float4 wz = *(const float4*)(Wcat + k * 192 + 64 + c0);
    float4 wn = *(const float4*)(Wcat + k * 192 + 128 + c0);
    float wra[4] = {wr.x, wr.y, wr.z, wr.w};
    float wza[4] = {wz.x, wz.y, wz.z, wz.w};
    float wna[4] = {wn.x, wn.y, wn.z, wn.w};
#pragma unroll
    for (int i = 0; i < 4; ++i) {
      float a = As[(r0 + i) * AST + k];
#pragma unroll
      for (int j = 0; j < 4; ++j) {
        aR[i][j]  = fmaf(a, wra[j], aR[i][j]);
        aZ[i][j]  = fmaf(a, wza[j], aZ[i][j]);
        aNi[i][j] = fmaf(a, wna[j], aNi[i][j]);
      }
    }
  }
  for (int k = 64; k < 128; ++k) {
    float4 wr = *(const float4*)(Wcat + k * 192 + c0);
    float4 wz = *(const float4*)(Wcat + k * 192 + 64 + c0);
    float4 wn = *(const float4*)(Wcat + k * 192 + 128 + c0);
    float wra[4] = {wr.x, wr.y, wr.z, wr.w};
    float wza[4] = {wz.x, wz.y, wz.z, wz.w};
    float wna[4] = {wn.x, wn.y, wn.z, wn.w};
#pragma unroll
    for (int i = 0; i < 4; ++i) {
      float a = As[(r0 + i) * AST + k];
#pragma unroll
      for (int j = 0; j < 4; ++j) {
        aR[i][j]  = fmaf(a, wra[j], aR[i][j]);
        aZ[i][j]  = fmaf(a, wza[j], aZ[i][j]);
        aNh[i][j] = fmaf(a, wna[j], aNh[i][j]);
      }
    }
  }

  float4 birv = *(const float4*)(bih + c0);
  float4 bhrv = *(const float4*)(bhh + c0);
  float4 bizv = *(const float4*)(bih + 64 + c0);
  float4 bhzv = *(const float4*)(bhh + 64 + c0);
  float4 binv = *(const float4*)(bih + 128 + c0);
  float4 bhnv = *(const float4*)(bhh + 128 + c0);
  float bir[4] = {birv.x, birv.y, birv.z, birv.w};
  float bhr[4] = {bhrv.x, bhrv.y, bhrv.z, bhrv.w};
  float biz[4] = {bizv.x, bizv.y, bizv.z, bizv.w};
  float bhz[4] = {bhzv.x, bhzv.y, bhzv.z, bhzv.w};
  float bin[4] = {binv.x, binv.y, binv.z, binv.w};
  float bhn[4] = {bhnv.x, bhnv.y, bhnv.z, bhnv.w};

  float oo[4][4];
#pragma unroll
  for (int i = 0; i < 4; ++i) {
    int r = rowBase + r0 + i;
#pragma unroll
    for (int j = 0; j < 4; ++j) {
      float rg = 1.f / (1.f + expf(-(aR[i][j] + bir[j] + bhr[j])));
      float zg = 1.f / (1.f + expf(-(aZ[i][j] + biz[j] + bhz[j])));
      float nc = tanhf(aNi[i][j] + bin[j] + rg * (aNh[i][j] + bhn[j]));
      float h0v = As[(r0 + i) * AST + 64 + c0 + j];
      oo[i][j] = (1.f - zg) * nc + zg * h0v;
    }
    if (r < NN)
      *(float4*)(hnew + (size_t)r * HD + c0) = make_float4(oo[i][0], oo[i][1], oo[i][2], oo[i][3]);
  }

  __syncthreads();
#pragma unroll
  for (int i = 0; i < 4; ++i)
    *(float4*)(&As[(r0 + i) * AST + c0]) = make_float4(oo[i][0], oo[i][1], oo[i][2], oo[i][3]);
  __syncthreads();

  int orow = tid >> 2;
  int oc0 = (tid & 3) * 4;
  if (rowBase + orow < NN) {
    float4 bpv = *(const float4*)(bp + oc0);
    float racc[4] = {bpv.x, bpv.y, bpv.z, bpv.w};
    for (int k = 0; k < HD; ++k) {
      float hv = As[orow * AST + k];
      float4 wp = *(const float4*)(Wp + k * TOUT + oc0);
      racc[0] = fmaf(hv, wp.x, racc[0]);
      racc[1] = fmaf(hv, wp.y, racc[1]);
      racc[2] = fmaf(hv, wp.z, racc[2]);
      racc[3] = fmaf(hv, wp.w, racc[3]);
    }
    *(float4*)(out + (size_t)(rowBase + orow) * TOUT + oc0) = make_float4(racc[0], racc[1], racc[2], racc[3]);
  }
}

extern "C" void kernel_launch(void* const* d_in, const int* in_sizes, int n_in,
                              void* d_out, int out_size, void* d_ws, size_t ws_size,
                              hipStream_t stream) {
  const float* x    = (const float*)d_in[0];
  const int*   ei   = (const int*)d_in[1];
  const float* prev = (const float*)d_in[2];
  const float* W1   = (const float*)d_in[3];
  const float* b1   = (const float*)d_in[4];
  const float* W2   = (const float*)d_in[5];
  const float* b2   = (const float*)d_in[6];
  const float* w_ih = (const float*)d_in[7];
  const float* w_hh = (const float*)d_in[8];
  const float* b_ih = (const float*)d_in[9];
  const float* b_hh = (const float*)d_in[10];
  const float* Wp   = (const float*)d_in[11];
  const float* bp   = (const float*)d_in[12];

  float* out  = (float*)d_out;                 // [NN,16]
  float* hnew = out + (size_t)NN * TOUT;       // [NN,64]

  char* ws = (char*)d_ws;
  float*    dinv    = (float*)(ws + 0);                    // 400,000
  int*      rowptr  = (int*)(ws + 400000);                 // 400,064
  int*      bcur    = (int*)(ws + 800064);                 // 1,564
  int*      bktBase = (int*)(ws + 801664);                 // 1,564
  int*      csr_src = (int*)(ws + 803264);                 // 12,800,000
  __half*   hwsH    = (__half*)(ws + 13603264);            // 12,800,000
  float*    bufB    = (float*)(ws + 26403264);             // 25,600,000 (packed u32 alias; CAP*NBUK*4 = 19.2MB)
  float*    bufC    = (float*)(ws + 52003264);             // 25,600,000
  float*    Wcat    = (float*)(ws + 77603264);             // 98,304
  unsigned* packed  = (unsigned*)bufB;

  const int* srcA = ei;
  const int* dstA = ei + NE;

  // ---- CSR build (no degree pre-pass) ----
  k_init<<<(NBUK + 255) / 256, 256, 0, stream>>>(bcur);
  k_p1<<<(NE + EPB - 1) / EPB, 256, 0, stream>>>(srcA, dstA, bcur, packed);
  k_scanb<<<1, 512, 0, stream>>>(bcur, bktBase, rowptr);
  k_p2big<<<NBUK, 256, 0, stream>>>(packed, bcur, bktBase, rowptr, dinv, csr_src);

  // ---- GCN layer 1 ----
  k_gemmh<FIN><<<dim3((NN + 63) / 64, 1), 256, 0, stream>>>(x, W1, hwsH, NN, HD, dinv);
  k_gather<<<(NN + 3) / 4, 256, 0, stream>>>(hwsH, rowptr, csr_src, dinv, b1, bufC);

  // ---- GCN layer 2 ----
  k_gemmh<HD><<<dim3((NN + 63) / 64, 1), 256, 0, stream>>>(bufC, W2, hwsH, NN, HD, dinv);
  k_gather<<<(NN + 3) / 4, 256, 0, stream>>>(hwsH, rowptr, csr_src, dinv, b2, bufC);

  // ---- fused GRU (K=128 GEMM + gates + readout) ----
  k_prep<<<(128 * 192 + 255) / 256, 256, 0, stream>>>(w_ih, w_hh, Wcat);
  k_grufused<<<(NN + 63) / 64, 256, 0, stream>>>(bufC, prev, Wcat, b_ih, b_hh, Wp, bp, hnew, out);
}

// Round 9
// 411.522 us; speedup vs baseline: 1.5381x; 1.0493x over previous
//
#include <hip/hip_runtime.h>
#include <hip/hip_fp16.h>
#include <math.h>

#define NN 100000
#define NE 3200000
#define FIN 128
#define HD 64
#define TOUT 16
#define BSH 8                        // 256 nodes per bucket
#define NBUK ((NN + 255) / 256)      // 391 buckets
#define EPB 8192                     // edges per P1 block
#define CAP 12288                    // slots per bucket (mean 8192, ~45 sigma headroom)

// ---------------- init bucket cursors to fixed-capacity region starts ----------------
__global__ __launch_bounds__(256) void k_init(int* __restrict__ bcur) {
  int t = blockIdx.x * 256 + threadIdx.x;
  if (t < NBUK) bcur[t] = t * CAP;
}

// ---------------- P1: block-local histogram + contiguous run reservation (fixed-cap buckets) ----------------
__global__ __launch_bounds__(256) void k_p1(const int* __restrict__ src, const int* __restrict__ dst,
                                            int* __restrict__ bcur, unsigned* __restrict__ packed) {
  __shared__ int hist[NBUK];
  __shared__ int base[NBUK];
  int t = threadIdx.x;
  int e0 = blockIdx.x * EPB;
  int e1 = e0 + EPB; if (e1 > NE) e1 = NE;

  for (int i = t; i < NBUK; i += 256) hist[i] = 0;
  __syncthreads();
  for (int e = e0 + t; e < e1; e += 256) atomicAdd(&hist[dst[e] >> BSH], 1);
  __syncthreads();
  for (int i = t; i < NBUK; i += 256) {
    int c = hist[i];
    base[i] = c ? atomicAdd(&bcur[i], c) : 0;
    hist[i] = 0;
  }
  __syncthreads();
  for (int e = e0 + t; e < e1; e += 256) {
    int d = dst[e];
    int b = d >> BSH;
    int p = base[b] + atomicAdd(&hist[b], 1);
    packed[p] = ((unsigned)(d & 255) << 17) | (unsigned)src[e];
  }
}

// ---------------- scan bucket totals -> global bucket bases ----------------
__global__ __launch_bounds__(512) void k_scanb(const int* __restrict__ bcur, int* __restrict__ bktBase,
                                               int* __restrict__ rowptr) {
  __shared__ int s[512];
  int t = threadIdx.x;
  int v = (t < NBUK) ? (bcur[t] - t * CAP) : 0;
  s[t] = v;
  __syncthreads();
  for (int off = 1; off < 512; off <<= 1) {
    int y = (t >= off) ? s[t - off] : 0;
    __syncthreads();
    s[t] += y;
    __syncthreads();
  }
  if (t < NBUK) bktBase[t] = s[t] - v;
  if (t == 0) rowptr[NN] = NE;
}

// ---------------- P2: per-bucket degree histogram + local scan + rowptr/dinv + CSR place ----------------
__global__ __launch_bounds__(256) void k_p2big(const unsigned* __restrict__ packed, const int* __restrict__ bcur,
                                               const int* __restrict__ bktBase, int* __restrict__ rowptr,
                                               float* __restrict__ dinv, int* __restrict__ csr_src) {
  __shared__ int degl[256];
  __shared__ int sc[256];
  __shared__ int cur[256];
  int b = blockIdx.x, t = threadIdx.x;
  int pbase = b * CAP;
  int cnt = bcur[b] - pbase;

  degl[t] = 0;
  __syncthreads();
  for (int i = t; i < cnt; i += 256) {
    unsigned v = packed[pbase + i];
    atomicAdd(&degl[v >> 17], 1);
  }
  __syncthreads();
  int dv = degl[t];
  sc[t] = dv;
  __syncthreads();
  for (int off = 1; off < 256; off <<= 1) {
    int y = (t >= off) ? sc[t - off] : 0;
    __syncthreads();
    sc[t] += y;
    __syncthreads();
  }
  int gpos = bktBase[b] + (sc[t] - dv);
  int node = (b << BSH) + t;
  if (node < NN) {
    rowptr[node] = gpos;
    dinv[node] = 1.0f / sqrtf((float)dv + 1.0f);   // +1 self-loop
  }
  cur[t] = gpos;
  __syncthreads();
  for (int i = t; i < cnt; i += 256) {
    unsigned pv = packed[pbase + i];
    int pos = atomicAdd(&cur[pv >> 17], 1);
    csr_src[pos] = (int)(pv & 0x1FFFFu);
  }
}

// ---------------- tiled GEMM with fp16 scaled output: Ch[n,M] = half((A@W) * scale[r]) ----------------
template<int K>
__global__ __launch_bounds__(256) void k_gemmh(const float* __restrict__ A, const float* __restrict__ W,
                                               __half* __restrict__ Ch, int n, int M,
                                               const float* __restrict__ scale) {
  constexpr int AS = K + 4;
  __shared__ float As[64 * AS];
  int tid = threadIdx.x;
  int rowBase = blockIdx.x * 64;
  int colBase = blockIdx.y * 64;
  int nrows = n - rowBase; if (nrows > 64) nrows = 64;

  for (int idx = tid * 4; idx < 64 * K; idx += 1024) {
    int row = idx / K;
    int k = idx - row * K;
    float4 v = make_float4(0.f, 0.f, 0.f, 0.f);
    if (row < nrows) v = *(const float4*)(A + (size_t)(rowBase + row) * K + k);
    *(float4*)(&As[row * AS + k]) = v;
  }
  __syncthreads();

  int tx = tid & 15, ty = tid >> 4;
  int c0 = colBase + tx * 4;
  int r0 = ty * 4;
  float acc[4][4] = {{0.f}};

  for (int k = 0; k < K; ++k) {
    float4 wv = *(const float4*)(W + (size_t)k * M + c0);
    float wa[4] = {wv.x, wv.y, wv.z, wv.w};
#pragma unroll
    for (int i = 0; i < 4; ++i) {
      float a = As[(r0 + i) * AS + k];
#pragma unroll
      for (int j = 0; j < 4; ++j) acc[i][j] = fmaf(a, wa[j], acc[i][j]);
    }
  }

#pragma unroll
  for (int i = 0; i < 4; ++i) {
    int r = rowBase + r0 + i;
    if (r < n) {
      float sc = scale[r];
      __half2 p0 = __floats2half2_rn(acc[i][0] * sc, acc[i][1] * sc);
      __half2 p1 = __floats2half2_rn(acc[i][2] * sc, acc[i][3] * sc);
      __half2* cp = (__half2*)(Ch + (size_t)r * M + c0);
      cp[0] = p0;
      cp[1] = p1;
    }
  }
}

// ---------------- gather (fp16 table, 4 edges/wave in flight, 8B loads) ----------------
__global__ __launch_bounds__(256) void k_gather(const __half* __restrict__ hws, const int* __restrict__ rowptr,
                                                const int* __restrict__ csr_src, const float* __restrict__ dinv,
                                                const float* __restrict__ b, float* __restrict__ h) {
  int node = blockIdx.x * 4 + (threadIdx.x >> 6);
  if (node >= NN) return;
  int lane = threadIdx.x & 63;
  int f4  = lane & 15;
  int grp = lane >> 4;
  int beg = rowptr[node], end = rowptr[node + 1];
  const uint2* hw2 = (const uint2*)hws;
  float4 acc = make_float4(0.f, 0.f, 0.f, 0.f);

  for (int base = beg; base < end; base += 64) {
    int m = end - base; if (m > 64) m = 64;
    int myS = (lane < m) ? csr_src[base + lane] : 0;
    int nq = m & ~3;
    int i = 0;
#pragma unroll 4
    for (; i < nq; i += 4) {
      int s = __shfl(myS, i + grp);
      uint2 u = hw2[(size_t)s * 16 + f4];
      float2 fa = __half22float2(*(__half2*)&u.x);
      float2 fb = __half22float2(*(__half2*)&u.y);
      acc.x += fa.x; acc.y += fa.y; acc.z += fb.x; acc.w += fb.y;
    }
    if (i < m) {
      int idx = i + grp;
      int s = __shfl(myS, idx < m ? idx : 0);
      if (idx < m) {
        uint2 u = hw2[(size_t)s * 16 + f4];
        float2 fa = __half22float2(*(__half2*)&u.x);
        float2 fb = __half22float2(*(__half2*)&u.y);
        acc.x += fa.x; acc.y += fa.y; acc.z += fb.x; acc.w += fb.y;
      }
    }
  }

  acc.x += __shfl_xor(acc.x, 16); acc.y += __shfl_xor(acc.y, 16);
  acc.z += __shfl_xor(acc.z, 16); acc.w += __shfl_xor(acc.w, 16);
  acc.x += __shfl_xor(acc.x, 32); acc.y += __shfl_xor(acc.y, 32);
  acc.z += __shfl_xor(acc.z, 32); acc.w += __shfl_xor(acc.w, 32);

  if (lane < 16) {
    uint2 u = hw2[(size_t)node * 16 + f4];
    float2 fa = __half22float2(*(__half2*)&u.x);
    float2 fb = __half22float2(*(__half2*)&u.y);
    acc.x += fa.x; acc.y += fa.y; acc.z += fb.x; acc.w += fb.y;
    float di = dinv[node];
    float4 bb = ((const float4*)b)[f4];
    float4 o;
    o.x = fmaxf(fmaf(di, acc.x, bb.x), 0.f);
    o.y = fmaxf(fmaf(di, acc.y, bb.y), 0.f);
    o.z = fmaxf(fmaf(di, acc.z, bb.z), 0.f);
    o.w = fmaxf(fmaf(di, acc.w, bb.w), 0.f);
    *(float4*)(h + (size_t)node * HD + f4 * 4) = o;
  }
}

// ---------------- prep: Wcat[k][192] = k<64 ? w_ih[:,k].T : w_hh[:,k-64].T ----------------
__global__ __launch_bounds__(256) void k_prep(const float* __restrict__ w_ih, const float* __restrict__ w_hh,
                                              float* __restrict__ Wcat) {
  int t = blockIdx.x * 256 + threadIdx.x;
  if (t >= 128 * 192) return;
  int k = t / 192, c = t - k * 192;
  Wcat[t] = (k < 64) ? w_ih[c * 64 + k] : w_hh[c * 64 + (k - 64)];
}

// ---------------- fused GRU: K=128 GEMM with LDS-staged weight chunks + gates + readout ----------------
// A-tile: 64 rows x 128 cols (h | h0), stride 132 (33.8KB). Weight chunk: 32 k-rows x 192 (24.6KB).
#define AST 132
__global__ __launch_bounds__(256) void k_grufused(const float* __restrict__ h, const float* __restrict__ prev,
                                                  const float* __restrict__ Wcat,
                                                  const float* __restrict__ bih, const float* __restrict__ bhh,
                                                  const float* __restrict__ Wp, const float* __restrict__ bp,
                                                  float* __restrict__ hnew, float* __restrict__ out) {
  __shared__ float As[64 * AST];      // 33,792 B
  __shared__ float Ws[32 * 192];      // 24,576 B
  int tid = threadIdx.x;
  int rowBase = blockIdx.x * 64;
  int nrows = NN - rowBase; if (nrows > 64) nrows = 64;

  for (int idx = tid * 4; idx < 64 * 64; idx += 1024) {
    int r = idx >> 6, k = idx & 63;
    float4 v = make_float4(0.f, 0.f, 0.f, 0.f);
    float4 w = make_float4(0.f, 0.f, 0.f, 0.f);
    if (r < nrows) {
      v = *(const float4*)(h + (size_t)(rowBase + r) * HD + k);
      w = *(const float4*)(prev + (size_t)(rowBase + r) * HD + k);
    }
    *(float4*)(&As[r * AST + k]) = v;
    *(float4*)(&As[r * AST + 64 + k]) = w;
  }

  int tx = tid & 15, ty = tid >> 4;
  int c0 = tx * 4;
  int r0 = ty * 4;
  float aR[4][4] = {{0.f}}, aZ[4][4] = {{0.f}}, aNi[4][4] = {{0.f}}, aNh[4][4] = {{0.f}};

#pragma unroll
  for (int kc = 0; kc < 4; ++kc) {
    __syncthreads();   // protect previous Ws use (and covers initial As staging on kc=0)
    {
      const float4* srcW = (const float4*)(Wcat + kc * 32 * 192);
      float4* dstW = (float4*)Ws;
#pragma unroll
      for (int j = 0; j < 6; ++j) dstW[tid + j * 256] = srcW[tid + j * 256];
    }
    __syncthreads();

    int kbase = kc * 32;
    for (int kk = 0; kk < 32; ++kk) {
      float4 wr = *(const float4*)(&Ws[kk * 192 + c0]);
      float4 wz = *(const float4*)(&Ws[kk * 192 + 64 + c0]);
      float4 wn = *(const float4*)(&Ws[kk * 192 + 128 + c0]);
      float wra[4] = {wr.x, wr.y, wr.z, wr.w};
      float wza[4] = {wz.x, wz.y, wz.z, wz.w};
      float wna[4] = {wn.x, wn.y, wn.z, wn.w};
      if (kc < 2) {
#pragma unroll
        for (int i = 0; i < 4; ++i) {
          float a = As[(r0 + i) * AST + kbase + kk];
#pragma unroll
          for (int j = 0; j < 4; ++j) {
            aR[i][j]  = fmaf(a, wra[j], aR[i][j]);
            aZ[i][j]  = fmaf(a, wza[j], aZ[i][j]);
            aNi[i][j] = fmaf(a, wna[j], aNi[i][j]);
          }
        }
      } else {
#pragma unroll
        for (int i = 0; i < 4; ++i) {
          float a = As[(r0 + i) * AST + kbase + kk];
#pragma unroll
          for (int j = 0; j < 4; ++j) {
            aR[i][j]  = fmaf(a, wra[j], aR[i][j]);
            aZ[i][j]  = fmaf(a, wza[j], aZ[i][j]);
            aNh[i][j] = fmaf(a, wna[j], aNh[i][j]);
          }
        }
      }
    }
  }

  float4 birv = *(const float4*)(bih + c0);
  float4 bhrv = *(const float4*)(bhh + c0);
  float4 bizv = *(const float4*)(bih + 64 + c0);
  float4 bhzv = *(const float4*)(bhh + 64 + c0);
  float4 binv = *(const float4*)(bih + 128 + c0);
  float4 bhnv = *(const float4*)(bhh + 128 + c0);
  float bir[4] = {birv.x, birv.y, birv.z, birv.w};
  float bhr[4] = {bhrv.x, bhrv.y, bhrv.z, bhrv.w};
  float biz[4] = {bizv.x, bizv.y, bizv.z, bizv.w};
  float bhz[4] = {bhzv.x, bhzv.y, bhzv.z, bhzv.w};
  float bin[4] = {binv.x, binv.y, binv.z, binv.w};
  float bhn[4] = {bhnv.x, bhnv.y, bhnv.z, bhnv.w};

  float oo[4][4];
#pragma unroll
  for (int i = 0; i < 4; ++i) {
    int r = rowBase + r0 + i;
#pragma unroll
    for (int j = 0; j < 4; ++j) {
      float rg = 1.f / (1.f + expf(-(aR[i][j] + bir[j] + bhr[j])));
      float zg = 1.f / (1.f + expf(-(aZ[i][j] + biz[j] + bhz[j])));
      float nc = tanhf(aNi[i][j] + bin[j] + rg * (aNh[i][j] + bhn[j]));
      float h0v = As[(r0 + i) * AST + 64 + c0 + j];
      oo[i][j] = (1.f - zg) * nc + zg * h0v;
    }
    if (r < NN)
      *(float4*)(hnew + (size_t)r * HD + c0) = make_float4(oo[i][0], oo[i][1], oo[i][2], oo[i][3]);
  }

  // ---- fused readout: stash hnew tile into LDS, out = hnew@Wp + bp ----
  __syncthreads();
#pragma unroll
  for (int i = 0; i < 4; ++i)
    *(float4*)(&As[(r0 + i) * AST + c0]) = make_float4(oo[i][0], oo[i][1], oo[i][2], oo[i][3]);
  __syncthreads();

  int orow = tid >> 2;
  int oc0 = (tid & 3) * 4;
  if (rowBase + orow < NN) {
    float4 bpv = *(const float4*)(bp + oc0);
    float racc[4] = {bpv.x, bpv.y, bpv.z, bpv.w};
    for (int k = 0; k < HD; ++k) {
      float hv = As[orow * AST + k];
      float4 wp = *(const float4*)(Wp + k * TOUT + oc0);
      racc[0] = fmaf(hv, wp.x, racc[0]);
      racc[1] = fmaf(hv, wp.y, racc[1]);
      racc[2] = fmaf(hv, wp.z, racc[2]);
      racc[3] = fmaf(hv, wp.w, racc[3]);
    }
    *(float4*)(out + (size_t)(rowBase + orow) * TOUT + oc0) = make_float4(racc[0], racc[1], racc[2], racc[3]);
  }
}

extern "C" void kernel_launch(void* const* d_in, const int* in_sizes, int n_in,
                              void* d_out, int out_size, void* d_ws, size_t ws_size,
                              hipStream_t stream) {
  const float* x    = (const float*)d_in[0];
  const int*   ei   = (const int*)d_in[1];
  const float* prev = (const float*)d_in[2];
  const float* W1   = (const float*)d_in[3];
  const float* b1   = (const float*)d_in[4];
  const float* W2   = (const float*)d_in[5];
  const float* b2   = (const float*)d_in[6];
  const float* w_ih = (const float*)d_in[7];
  const float* w_hh = (const float*)d_in[8];
  const float* b_ih = (const float*)d_in[9];
  const float* b_hh = (const float*)d_in[10];
  const float* Wp   = (const float*)d_in[11];
  const float* bp   = (const float*)d_in[12];

  float* out  = (float*)d_out;                 // [NN,16]
  float* hnew = out + (size_t)NN * TOUT;       // [NN,64]

  char* ws = (char*)d_ws;
  float*    dinv    = (float*)(ws + 0);                    // 400,000
  int*      rowptr  = (int*)(ws + 400000);                 // 400,064
  int*      bcur    = (int*)(ws + 800064);                 // 1,564
  int*      bktBase = (int*)(ws + 801664);                 // 1,564
  int*      csr_src = (int*)(ws + 803264);                 // 12,800,000
  __half*   hwsH    = (__half*)(ws + 13603264);            // 12,800,000
  float*    bufB    = (float*)(ws + 26403264);             // 25,600,000 (packed u32 alias; CAP*NBUK*4 = 19.2MB)
  float*    bufC    = (float*)(ws + 52003264);             // 25,600,000
  float*    Wcat    = (float*)(ws + 77603264);             // 98,304
  unsigned* packed  = (unsigned*)bufB;

  const int* srcA = ei;
  const int* dstA = ei + NE;

  // ---- CSR build (no degree pre-pass) ----
  k_init<<<(NBUK + 255) / 256, 256, 0, stream>>>(bcur);
  k_p1<<<(NE + EPB - 1) / EPB, 256, 0, stream>>>(srcA, dstA, bcur, packed);
  k_scanb<<<1, 512, 0, stream>>>(bcur, bktBase, rowptr);
  k_p2big<<<NBUK, 256, 0, stream>>>(packed, bcur, bktBase, rowptr, dinv, csr_src);

  // ---- GCN layer 1 ----
  k_gemmh<FIN><<<dim3((NN + 63) / 64, 1), 256, 0, stream>>>(x, W1, hwsH, NN, HD, dinv);
  k_gather<<<(NN + 3) / 4, 256, 0, stream>>>(hwsH, rowptr, csr_src, dinv, b1, bufC);

  // ---- GCN layer 2 ----
  k_gemmh<HD><<<dim3((NN + 63) / 64, 1), 256, 0, stream>>>(bufC, W2, hwsH, NN, HD, dinv);
  k_gather<<<(NN + 3) / 4, 256, 0, stream>>>(hwsH, rowptr, csr_src, dinv, b2, bufC);

  // ---- fused GRU (K=128 GEMM + gates + readout) ----
  k_prep<<<(128 * 192 + 255) / 256, 256, 0, stream>>>(w_ih, w_hh, Wcat);
  k_grufused<<<(NN + 63) / 64, 256, 0, stream>>>(bufC, prev, Wcat, b_ih, b_hh, Wp, bp, hnew, out);
}